// Round 5
// baseline (357.233 us; speedup 1.0000x reference)
//
#include <hip/hip_runtime.h>

#define S_SCALE 30.0f
#define COS_M 0.8775825618903728f
#define SIN_M 0.479425538604203f
#define TH_C (-0.8775825618903728f)
#define MM_C 0.2397127693021015f

#define BD 512
#define DD 512
#define CC 100000
#define NCB2 782            // ceil(100000/128) col-blocks
#define LASTB2 781
#define NPART 1564          // 782 col-blocks x 2 col-groups of 64

typedef __bf16 bf16x8 __attribute__((ext_vector_type(8)));
typedef float  f32x4  __attribute__((ext_vector_type(4)));

#define AS1 __attribute__((address_space(1)))
#define AS3 __attribute__((address_space(3)))

// ---------------- Kernel 1: concat + normalize -> k-tiled bf16 A_t[16][512][32];
// one WAVE per row, no barriers, fully vectorized. Also label-column cosine/phi. ------
__global__ __launch_bounds__(256) void k_prep(const float* __restrict__ img,
                                              const float* __restrict__ prof,
                                              const float* __restrict__ W,
                                              const int* __restrict__ lab,
                                              __bf16* __restrict__ At,
                                              float* __restrict__ sphi,
                                              float* __restrict__ scos) {
    const int t = threadIdx.x;
    const int wave = t >> 6, l = t & 63;
    const int row = blockIdx.x * 4 + wave;          // 128 blocks x 4 waves = 512 rows
    const float* src = (row < 256) ? (img + (size_t)row * DD) : (prof + (size_t)(row - 256) * DD);
    float4 v0 = ((const float4*)src)[l * 2];
    float4 v1 = ((const float4*)src)[l * 2 + 1];
    float s = v0.x * v0.x + v0.y * v0.y + v0.z * v0.z + v0.w * v0.w
            + v1.x * v1.x + v1.y * v1.y + v1.z * v1.z + v1.w * v1.w;
    #pragma unroll
    for (int o = 1; o < 64; o <<= 1) s += __shfl_xor(s, o);
    float r = rsqrtf(s);
    bf16x8 a;
    a[0] = (__bf16)(v0.x * r); a[1] = (__bf16)(v0.y * r);
    a[2] = (__bf16)(v0.z * r); a[3] = (__bf16)(v0.w * r);
    a[4] = (__bf16)(v1.x * r); a[5] = (__bf16)(v1.y * r);
    a[6] = (__bf16)(v1.z * r); a[7] = (__bf16)(v1.w * r);
    // k-tiled layout: element (row, d) -> At[(d>>5)*16384 + row*32 + (d&31)]
    *(bf16x8*)(At + (size_t)(l >> 2) * (BD * 32) + row * 32 + (l & 3) * 8) = a;

    // label-column cosine (on bf16-truncated values, matching the GEMM)
    const int c = lab[row & 255];
    const float4* wc = (const float4*)(W + (size_t)c * DD);
    float4 w0 = wc[l * 2], w1 = wc[l * 2 + 1];
    float wb0 = (float)(__bf16)w0.x, wb1 = (float)(__bf16)w0.y;
    float wb2 = (float)(__bf16)w0.z, wb3 = (float)(__bf16)w0.w;
    float wb4 = (float)(__bf16)w1.x, wb5 = (float)(__bf16)w1.y;
    float wb6 = (float)(__bf16)w1.z, wb7 = (float)(__bf16)w1.w;
    float dot = (float)a[0] * wb0 + (float)a[1] * wb1 + (float)a[2] * wb2 + (float)a[3] * wb3
              + (float)a[4] * wb4 + (float)a[5] * wb5 + (float)a[6] * wb6 + (float)a[7] * wb7;
    float wsq = wb0 * wb0 + wb1 * wb1 + wb2 * wb2 + wb3 * wb3
              + wb4 * wb4 + wb5 * wb5 + wb6 * wb6 + wb7 * wb7;
    #pragma unroll
    for (int o = 1; o < 64; o <<= 1) { dot += __shfl_xor(dot, o); wsq += __shfl_xor(wsq, o); }
    if (l == 0) {
        float cs = dot * rsqrtf(wsq);
        float sn = sqrtf(fmaxf(0.f, fminf(1.f, 1.f - cs * cs)));
        float phi = cs * COS_M - sn * SIN_M;
        if (!(cs > TH_C)) phi = cs - MM_C;
        sphi[row] = S_SCALE * phi;
        scos[row] = S_SCALE * cs;
    }
}

// ---------------- Kernel 2: MFMA GEMM, m97 geometry: 128 rows x 128 cols per
// 256-thread block, BK=32, LDS 33KB -> 3 blocks/CU (12 waves of TLP).
// Grid 4 row-blocks x 782 col-blocks = 3128 = 8*391 (bijective XCD swizzle;
// the 4 row-siblings sharing a W panel run adjacent on one XCD -> L2 reuse).
// Simple m97 schedule: __syncthreads per K-step, glds-after-barrier,
// W reg-staged 1 tile ahead with cvt deferred one iteration. ----------------
__global__ __launch_bounds__(256, 3) void k_gemm(const __bf16* __restrict__ At,
                                                 const float* __restrict__ W,
                                                 float* __restrict__ part) {
    __shared__ __bf16 As[2][128 * 32];   // 2 x 8 KB
    __shared__ __bf16 Bs[2][128 * 32];   // 2 x 8 KB

    const int t = threadIdx.x;
    const int bid = blockIdx.x;
    const int swz = (bid & 7) * 391 + (bid >> 3);   // 3128 = 8*391, bijective
    const int rb = swz & 3;                         // row block (128 rows)
    const int cb = swz >> 2;                        // col block (128 cols), 0..781
    const int wave = t >> 6, lane = t & 63, q = lane >> 4, m16 = lane & 15;
    const int wr = wave >> 1, wc = wave & 1;        // wave quadrant: 64r x 64c

    // fragment read offset (elements), XOR chunk swizzle
    const int frag_off = m16 * 32 + ((q ^ ((m16 >> 1) & 3)) << 3);

    // W staging: thread t -> col t>>1 (0..127), half h = t&1 (k-offset h*16)
    const int wcol = t >> 1, h = t & 1;
    const int gc = cb * 128 + wcol;
    const float* wp = W + (size_t)(gc < CC ? gc : 0) * DD + h * 16;
    // Bs write offsets (elements) for logical 16B chunks h*2, h*2+1
    const int bofs0 = wcol * 32 + (((h * 2 + 0) ^ ((wcol >> 1) & 3)) << 3);
    const int bofs1 = wcol * 32 + (((h * 2 + 1) ^ ((wcol >> 1) & 3)) << 3);

    // glds source pre-swizzle (bytes): rows t>>2 (+64 on round 1)
    const int srcswz = ((t >> 2) << 6) + ((((t & 3) ^ ((t >> 3) & 3))) << 4);
    const char* abase = (const char*)At + (size_t)rb * 8192 + srcswz;

    f32x4 acc[4][4] = {};
    float sq = 0.f;
    float4 wr0, wr1, wr2, wr3;           // raw W(next) float4s
    bf16x8 nb0, nb1;                     // converted W(cur+1) ready for ds_write

#define GLDS_TILE(kt, buf)                                                              \
    {                                                                                   \
        _Pragma("unroll")                                                               \
        for (int rr = 0; rr < 2; ++rr) {                                                \
            __builtin_amdgcn_global_load_lds(                                           \
                (AS1 void*)(abase + (size_t)(kt) * 32768 + rr * 4096),                  \
                (AS3 void*)((char*)(&As[buf][0]) + rr * 4096 + wave * 1024),            \
                16, 0, 0);                                                              \
        }                                                                               \
    }

#define LOADW(n)                                                                        \
    {                                                                                   \
        wr0 = *(const float4*)(wp + (n) * 32);                                          \
        wr1 = *(const float4*)(wp + (n) * 32 + 4);                                      \
        wr2 = *(const float4*)(wp + (n) * 32 + 8);                                      \
        wr3 = *(const float4*)(wp + (n) * 32 + 12);                                     \
    }

#define CVTW()                                                                          \
    {                                                                                   \
        nb0[0] = (__bf16)wr0.x; nb0[1] = (__bf16)wr0.y;                                 \
        nb0[2] = (__bf16)wr0.z; nb0[3] = (__bf16)wr0.w;                                 \
        nb0[4] = (__bf16)wr1.x; nb0[5] = (__bf16)wr1.y;                                 \
        nb0[6] = (__bf16)wr1.z; nb0[7] = (__bf16)wr1.w;                                 \
        nb1[0] = (__bf16)wr2.x; nb1[1] = (__bf16)wr2.y;                                 \
        nb1[2] = (__bf16)wr2.z; nb1[3] = (__bf16)wr2.w;                                 \
        nb1[4] = (__bf16)wr3.x; nb1[5] = (__bf16)wr3.y;                                 \
        nb1[6] = (__bf16)wr3.z; nb1[7] = (__bf16)wr3.w;                                 \
        float f;                                                                        \
        f = (float)nb0[0]; sq += f * f; f = (float)nb0[1]; sq += f * f;                 \
        f = (float)nb0[2]; sq += f * f; f = (float)nb0[3]; sq += f * f;                 \
        f = (float)nb0[4]; sq += f * f; f = (float)nb0[5]; sq += f * f;                 \
        f = (float)nb0[6]; sq += f * f; f = (float)nb0[7]; sq += f * f;                 \
        f = (float)nb1[0]; sq += f * f; f = (float)nb1[1]; sq += f * f;                 \
        f = (float)nb1[2]; sq += f * f; f = (float)nb1[3]; sq += f * f;                 \
        f = (float)nb1[4]; sq += f * f; f = (float)nb1[5]; sq += f * f;                 \
        f = (float)nb1[6]; sq += f * f; f = (float)nb1[7]; sq += f * f;                 \
    }

#define WRITEBS(buf)                                                                    \
    {                                                                                   \
        *(bf16x8*)(&Bs[buf][bofs0]) = nb0;                                              \
        *(bf16x8*)(&Bs[buf][bofs1]) = nb1;                                              \
    }

    // ---- prologue: A(0) glds; W(0) load+cvt (full latency once); Bs[0]; W(1) ----
    GLDS_TILE(0, 0);
    LOADW(0);
    CVTW();
    WRITEBS(0);
    LOADW(1);

    #pragma unroll
    for (int kt = 0; kt < 16; ++kt) {
        __syncthreads();                     // As/Bs[(kt)&1] ready; prev readers done
        if (kt < 15) {
            GLDS_TILE(kt + 1, (kt + 1) & 1); // A(kt+1), lands by next barrier
            CVTW();                          // W(kt+1): loaded last iter (vmcnt skips glds)
            WRITEBS((kt + 1) & 1);
        }
        if (kt < 14) LOADW(kt + 2);          // raw W(kt+2), cvt next iter

        bf16x8 bfrag[4], afrag[4];
        #pragma unroll
        for (int j = 0; j < 4; ++j)
            bfrag[j] = *(const bf16x8*)(&Bs[kt & 1][wc * 2048 + j * 512 + frag_off]);
        #pragma unroll
        for (int i = 0; i < 4; ++i)
            afrag[i] = *(const bf16x8*)(&As[kt & 1][wr * 2048 + i * 512 + frag_off]);
        #pragma unroll
        for (int i = 0; i < 4; ++i) {
            #pragma unroll
            for (int j = 0; j < 4; ++j)
                acc[i][j] = __builtin_amdgcn_mfma_f32_16x16x32_bf16(
                    afrag[i], bfrag[j], acc[i][j], 0, 0, 0);
        }
    }

    // column sumsq -> csq[128], overlaid on As (done with it)
    __syncthreads();
    float* csq = (float*)&As[0][0];
    sq += __shfl_xor(sq, 1);
    if (h == 0) csq[wcol] = sq;
    __syncthreads();

    // epilogue: partial sum of exp(S * cosine) per row, per 64-col wave group
    const bool lastb = (cb == LASTB2);
    float inv[4]; bool val[4];
    #pragma unroll
    for (int j = 0; j < 4; ++j) {
        int ct = wc * 64 + j * 16 + m16;
        val[j] = (!lastb) || (ct < 32);      // last col-block: 32 valid cols
        inv[j] = rsqrtf(csq[ct]) * S_SCALE;
    }
    #pragma unroll
    for (int i = 0; i < 4; ++i) {
        #pragma unroll
        for (int r = 0; r < 4; ++r) {
            float e = 0.f;
            #pragma unroll
            for (int j = 0; j < 4; ++j)
                if (val[j]) e += __expf(acc[i][j][r] * inv[j]);
            e += __shfl_xor(e, 1);
            e += __shfl_xor(e, 2);
            e += __shfl_xor(e, 4);
            e += __shfl_xor(e, 8);
            if (m16 == 0)
                part[((size_t)cb * 2 + wc) * BD + rb * 128 + wr * 64 + i * 16 + q * 4 + r] = e;
        }
    }
#undef GLDS_TILE
#undef LOADW
#undef CVTW
#undef WRITEBS
}

// ---------------- Kernel 3a: parallel partial row-sums over column blocks ----------------
__global__ __launch_bounds__(256) void k_reduce1(const float* __restrict__ part,
                                                 float* __restrict__ rowpart) {
    const int b = blockIdx.x;
    const int rg = b >> 5, cp = b & 31;
    const int t = threadIdx.x;
    const int rl = t & 63, ph = t >> 6;     // 4 phases
    const int r0 = rg * 64;
    float s = 0.f;
    for (int c0 = cp * 4 + ph; c0 < NPART; c0 += 128)
        s += part[(size_t)c0 * BD + r0 + rl];
    __shared__ float buf[256];
    buf[t] = s;
    __syncthreads();
    if (t < 64)
        rowpart[(size_t)cp * BD + r0 + t] = buf[t] + buf[t + 64] + buf[t + 128] + buf[t + 192];
}

// ---------------- Kernel 3b: final logsumexp + label correction + mean (1 block) --------
__global__ __launch_bounds__(256) void k_final(const float* __restrict__ rowpart,
                                               const float* __restrict__ sphi,
                                               const float* __restrict__ scos,
                                               float* __restrict__ out) {
    const int t = threadIdx.x;
    float a = 0.f;
    for (int r = t; r < BD; r += 256) {
        float total = 0.f;
        #pragma unroll
        for (int cp = 0; cp < 32; ++cp)
            total += rowpart[(size_t)cp * BD + r];
        float lse = logf(total);
        float sp = sphi[r], sc = scos[r];
        float corr = log1pf(__expf(sp - lse) - __expf(sc - lse));
        a += lse + corr - sp;
    }
    for (int o = 1; o < 64; o <<= 1) a += __shfl_xor(a, o);
    __shared__ float wsum[4];
    if ((t & 63) == 0) wsum[t >> 6] = a;
    __syncthreads();
    if (t == 0) out[0] = (wsum[0] + wsum[1] + wsum[2] + wsum[3]) * (1.0f / 512.0f);
}

extern "C" void kernel_launch(void* const* d_in, const int* in_sizes, int n_in,
                              void* d_out, int out_size, void* d_ws, size_t ws_size,
                              hipStream_t stream) {
    const float* img  = (const float*)d_in[0];
    const float* prof = (const float*)d_in[1];
    const float* W    = (const float*)d_in[2];
    const int*   lab  = (const int*)d_in[3];

    char* ws = (char*)d_ws;
    __bf16* At     = (__bf16*)ws;                  // 512*512*2 = 524288 B (k-tiled)
    float* sphi    = (float*)(ws + 524288);        // 2048 B
    float* scos    = (float*)(ws + 526336);        // 2048 B
    float* part    = (float*)(ws + 528384);        // 1564*512*4 = 3,203,072 B
    float* rowpart = (float*)(ws + 3731456);       // 32*512*4 = 65,536 B

    k_prep<<<128, 256, 0, stream>>>(img, prof, W, lab, At, sphi, scos);
    k_gemm<<<4 * NCB2, 256, 0, stream>>>(At, W, part);
    k_reduce1<<<256, 256, 0, stream>>>(part, rowpart);
    k_final<<<1, 256, 0, stream>>>(rowpart, sphi, scos, (float*)d_out);
}